// Round 2
// 780.532 us; speedup vs baseline: 1.0122x; 1.0122x over previous
//
#include <hip/hip_runtime.h>

#define HXc 64
#define HYc 64
#define Uc  512
#define Vc  512
#define Lc  16

typedef float v4f __attribute__((ext_vector_type(4)));
typedef float v2f __attribute__((ext_vector_type(2)));

struct BL {
    const float* a11;
    const float* a21;
    const float* a12;
    const float* a22;
    float ir, jr;
};

__device__ __forceinline__ v4f ld4(const float* p) {
    return *reinterpret_cast<const v4f*>(p);
}

__device__ __forceinline__ BL mk(const float* __restrict__ base, int mm,
                                 float fi, float fj, int I, int J, int chan) {
    BL b;
    int i1 = (int)floorf(fi);
    int j1 = (int)floorf(fj);
    b.ir = fi - (float)i1;
    b.jr = fj - (float)j1;
    int i2 = (i1 + 1 == I) ? 0 : (i1 + 1);
    int j2 = (j1 + 1 == J) ? 0 : (j1 + 1);
    const float* p = base + ((size_t)mm * I * J) * Lc + chan;
    b.a11 = p + (size_t)(i1 * J + j1) * Lc;
    b.a21 = p + (size_t)(i2 * J + j1) * Lc;
    b.a12 = p + (size_t)(i1 * J + j2) * Lc;
    b.a22 = p + (size_t)(i2 * J + j2) * Lc;
    return b;
}

__device__ __forceinline__ v4f blend(v4f c11, v4f c21, v4f c12, v4f c22,
                                     float ir, float jr) {
    float oir = 1.0f - ir;
    float ojr = 1.0f - jr;
    v4f top = c11 * oir + c21 * ir;
    v4f bot = c12 * oir + c22 * ir;
    return top * ojr + bot * jr;
}

__global__ __launch_bounds__(256) void triplane_kernel(
    const int*   __restrict__ m_arr,
    const float* __restrict__ h,
    const float* __restrict__ u_arr,
    const float* __restrict__ v_arr,
    const float* __restrict__ Fxy,
    const float* __restrict__ Fxu,
    const float* __restrict__ Fxv,
    const float* __restrict__ Fyu,
    const float* __restrict__ Fyv,
    const float* __restrict__ Fuv,
    float* __restrict__ out,
    int N)
{
    int tid = blockIdx.x * blockDim.x + threadIdx.x;
    int n   = tid >> 2;   // point index
    int sub = tid & 3;    // which float4 slice of the 16 channels
    if (n >= N) return;

    // read-once per-point inputs: nontemporal (no L2 allocate)
    v2f hh = __builtin_nontemporal_load(reinterpret_cast<const v2f*>(h) + n);
    float uu = __builtin_nontemporal_load(u_arr + n);
    float vv = __builtin_nontemporal_load(v_arr + n);
    int   mm = __builtin_nontemporal_load(m_arr + n);

    float ind_hx = (hh.x + 1.0f) * 0.5f * (float)HXc;
    float ind_hy = (hh.y + 1.0f) * 0.5f * (float)HYc;
    if (ind_hx == (float)HXc) ind_hx = (float)(HXc - 1);
    if (ind_hy == (float)HYc) ind_hy = (float)(HYc - 1);
    float ind_u = uu * (float)Uc;
    float ind_v = vv * (float)Vc;
    if (ind_u == (float)Uc) ind_u = (float)(Uc - 1);
    if (ind_v == (float)Vc) ind_v = (float)(Vc - 1);

    int chan = sub * 4;

    // ---- phase 1: compute ALL 24 corner addresses ----
    BL b0 = mk(Fxy, mm, ind_hx, ind_hy, HXc, HYc, chan);
    BL b1 = mk(Fxu, mm, ind_hx, ind_u,  HXc, Uc,  chan);
    BL b2 = mk(Fxv, mm, ind_hx, ind_v,  HXc, Vc,  chan);
    BL b3 = mk(Fyu, mm, ind_hy, ind_u,  HYc, Uc,  chan);
    BL b4 = mk(Fyv, mm, ind_hy, ind_v,  HYc, Vc,  chan);
    BL b5 = mk(Fuv, mm, ind_u,  ind_v,  Uc,  Vc,  chan);

    // ---- phase 2: issue ALL 24 loads before any consumption (max MLP) ----
    v4f c0a = ld4(b0.a11); v4f c0b = ld4(b0.a21); v4f c0c = ld4(b0.a12); v4f c0d = ld4(b0.a22);
    v4f c1a = ld4(b1.a11); v4f c1b = ld4(b1.a21); v4f c1c = ld4(b1.a12); v4f c1d = ld4(b1.a22);
    v4f c2a = ld4(b2.a11); v4f c2b = ld4(b2.a21); v4f c2c = ld4(b2.a12); v4f c2d = ld4(b2.a22);
    v4f c3a = ld4(b3.a11); v4f c3b = ld4(b3.a21); v4f c3c = ld4(b3.a12); v4f c3d = ld4(b3.a22);
    v4f c4a = ld4(b4.a11); v4f c4b = ld4(b4.a21); v4f c4c = ld4(b4.a12); v4f c4d = ld4(b4.a22);
    v4f c5a = ld4(b5.a11); v4f c5b = ld4(b5.a21); v4f c5c = ld4(b5.a12); v4f c5d = ld4(b5.a22);

    // keep all loads issued above this point; blends below consume in order,
    // so the compiler emits descending vmcnt waits (vmcnt(20), vmcnt(16), ...)
    __builtin_amdgcn_sched_barrier(0);

    float* o = out + (size_t)n * 96 + chan;

    v4f r0 = blend(c0a, c0b, c0c, c0d, b0.ir, b0.jr);
    __builtin_nontemporal_store(r0, reinterpret_cast<v4f*>(o + 0 * Lc));
    v4f r1 = blend(c1a, c1b, c1c, c1d, b1.ir, b1.jr);
    __builtin_nontemporal_store(r1, reinterpret_cast<v4f*>(o + 1 * Lc));
    v4f r2 = blend(c2a, c2b, c2c, c2d, b2.ir, b2.jr);
    __builtin_nontemporal_store(r2, reinterpret_cast<v4f*>(o + 2 * Lc));
    v4f r3 = blend(c3a, c3b, c3c, c3d, b3.ir, b3.jr);
    __builtin_nontemporal_store(r3, reinterpret_cast<v4f*>(o + 3 * Lc));
    v4f r4 = blend(c4a, c4b, c4c, c4d, b4.ir, b4.jr);
    __builtin_nontemporal_store(r4, reinterpret_cast<v4f*>(o + 4 * Lc));
    v4f r5 = blend(c5a, c5b, c5c, c5d, b5.ir, b5.jr);
    __builtin_nontemporal_store(r5, reinterpret_cast<v4f*>(o + 5 * Lc));
}

extern "C" void kernel_launch(void* const* d_in, const int* in_sizes, int n_in,
                              void* d_out, int out_size, void* d_ws, size_t ws_size,
                              hipStream_t stream) {
    // setup_inputs order: r(unused), m, h, u, v, Fxy, Fxu, Fxv, Fyu, Fyv, Fuv
    const int*   m_arr = (const int*)  d_in[1];
    const float* h     = (const float*)d_in[2];
    const float* u_arr = (const float*)d_in[3];
    const float* v_arr = (const float*)d_in[4];
    const float* Fxy   = (const float*)d_in[5];
    const float* Fxu   = (const float*)d_in[6];
    const float* Fxv   = (const float*)d_in[7];
    const float* Fyu   = (const float*)d_in[8];
    const float* Fyv   = (const float*)d_in[9];
    const float* Fuv   = (const float*)d_in[10];
    float* out = (float*)d_out;

    int N = in_sizes[0];
    int total_threads = 4 * N;
    dim3 block(256);
    dim3 grid((total_threads + 255) / 256);
    triplane_kernel<<<grid, block, 0, stream>>>(m_arr, h, u_arr, v_arr,
                                                Fxy, Fxu, Fxv, Fyu, Fyv, Fuv,
                                                out, N);
}